// Round 16
// baseline (626.384 us; speedup 1.0000x reference)
//
#include <hip/hip_runtime.h>
#include <hip/hip_bf16.h>

#define BB 512
#define TT 256

typedef __attribute__((ext_vector_type(8))) short bf16x8;
typedef __attribute__((ext_vector_type(4))) float f32x4;

__device__ __forceinline__ unsigned short f2b(float f) {
    union { float f; unsigned u; } v; v.f = f;
    unsigned r = v.u + 0x7FFFu + ((v.u >> 16) & 1u);
    return (unsigned short)(r >> 16);
}
__device__ __forceinline__ float b2f(unsigned short h) {
    union { unsigned u; float f; } v; v.u = ((unsigned)h) << 16;
    return v.f;
}
__device__ __forceinline__ ushort2 pk2(float a, float b) {
    __hip_bfloat162 h = __float22bfloat162_rn(float2{a, b});
    union { __hip_bfloat162 h; ushort2 u; } v; v.h = h; return v.u;
}

// B-layout per (s,t): 16-batch x K shorts, addr(b,k) = (k>>3)*128 + b*8 + (k&7).
// B-frag kc = one b128 at kc*512 + rdo (rdo = quad*128 + l15*8);
// D-tile mt write = ushort4 at wro + mt*256.

// ---------------- fp32 x -> bf16 B-layout tiles ----------------
__global__ __launch_bounds__(256) void cvt_tile(const float* __restrict__ x,
                                                unsigned short* __restrict__ xb) {
    const int blk = blockIdx.x;            // s*256 + t
    const int s = blk >> 8, t = blk & 255;
    const int tid = threadIdx.x;
    const int b = (tid >> 1) & 15;
    const int f0 = (tid >> 5) * 8 + (tid & 1) * 4;
    float4 v = *reinterpret_cast<const float4*>(
        &x[(((size_t)(s * 16 + b) * TT) + t) * 64 + f0]);
    ushort2 lo = pk2(v.x, v.y), hi = pk2(v.z, v.w);
    ushort4 o; o.x = lo.x; o.y = lo.y; o.z = hi.x; o.w = hi.y;
    *reinterpret_cast<ushort4*>(&xb[(size_t)blk * 1024 + tid * 4]) = o;
}

// ---------------- 4-layer skewed fused RNN + dense, wave-specialized --------
// 8 waves: w0,w1 = L1(64 cols)+L4(32 cols)+dense tap; w2-5 = L2(64 cols);
// w6,7 = L3(64 cols). wreg[48] holds the wave's weights (AGPR-resident is
// fine: gfx950 MFMA reads A from AGPR); wreg[36..39] double as w0/w1 x parity
// prefetch. Bias enters as C operand of each layer's first input-MFMA.
// DENSE FUSED: w0/w1 accumulate out[b] += h4(t)·Wd[t] in fp32 registers each
// step (Wd prefetched 2 steps ahead, parity buffers); final 128-float LDS
// reduce writes out. No H4 global tensor, no separate dense kernel.
__global__ __launch_bounds__(512) __attribute__((amdgpu_waves_per_eu(2, 2))) void rnn4(
    const unsigned short* __restrict__ Xb,
    const float* __restrict__ Wx1, const float* __restrict__ Wh1, const float* __restrict__ b1,
    const float* __restrict__ Wx2, const float* __restrict__ Wh2, const float* __restrict__ b2,
    const float* __restrict__ Wx3, const float* __restrict__ Wh3, const float* __restrict__ b3,
    const float* __restrict__ Wx4, const float* __restrict__ Wh4, const float* __restrict__ b4,
    const float* __restrict__ Wd, const float* __restrict__ bd,
    float* __restrict__ out) {
    const int tid = threadIdx.x;
    const int s = blockIdx.x;
    const int w = tid >> 6;
    const int lane = tid & 63;
    const int l15 = lane & 15;
    const int quad = lane >> 4;
    const int rdo = quad * 128 + l15 * 8;

    // LDS: h1[0,2048) h2[2048,6144) h3[6144,8192) h4[8192,9216) per parity
    __shared__ __align__(16) unsigned short hall[2][9216];

    bf16x8 wreg[48];
    f32x4 bvv[6];

#define LOADW(BASE, WP, H_, CB, KC_, MT_)                                          \
    _Pragma("unroll")                                                              \
    for (int mt = 0; mt < MT_; ++mt) {                                             \
        int m = (CB) + mt * 16 + l15;                                              \
        _Pragma("unroll")                                                          \
        for (int kc = 0; kc < KC_; ++kc)                                           \
            _Pragma("unroll")                                                      \
            for (int j = 0; j < 8; ++j)                                            \
                wreg[(BASE) + kc * MT_ + mt][j] =                                  \
                    (short)f2b(WP[(kc * 32 + quad * 8 + j) * H_ + m]);             \
    }
#define LOADBF(OFF, BP, CB, MT_)                                                   \
    _Pragma("unroll")                                                              \
    for (int mt = 0; mt < MT_; ++mt) {                                             \
        float4 t4v = *reinterpret_cast<const float4*>((BP) + (CB) + mt * 16 + quad * 4); \
        bvv[(OFF) + mt][0] = t4v.x; bvv[(OFF) + mt][1] = t4v.y;                    \
        bvv[(OFF) + mt][2] = t4v.z; bvv[(OFF) + mt][3] = t4v.w;                    \
    }

    if (w < 2) {
        LOADW(0,  Wh1, 128, w * 64, 4, 4)
        LOADW(16, Wx1, 128, w * 64, 2, 4)
        LOADW(24, Wh4, 64,  w * 32, 2, 2)
        LOADW(28, Wx4, 64,  w * 32, 4, 2)
        LOADBF(0, b1, w * 64, 4)
        LOADBF(4, b4, w * 32, 2)
    } else if (w < 6) {
        LOADW(0,  Wh2, 256, (w - 2) * 64, 8, 4)
        LOADW(32, Wx2, 256, (w - 2) * 64, 4, 4)
        LOADBF(0, b2, (w - 2) * 64, 4)
    } else {
        LOADW(0,  Wh3, 128, (w - 6) * 64, 4, 4)
        LOADW(16, Wx3, 128, (w - 6) * 64, 8, 4)
        LOADBF(0, b3, (w - 6) * 64, 4)
    }
#undef LOADW
#undef LOADBF

    for (int i = tid; i < 2 * 9216; i += 512) (&hall[0][0])[i] = 0;

    const unsigned short* Xs = Xb + (size_t)s * TT * 1024;

    // x parity prefetch into wreg[36..39]: [36,37] even t, [38,39] odd t
    if (w < 2) {
#pragma unroll
        for (int kx = 0; kx < 2; ++kx) {
            wreg[36 + kx] = *reinterpret_cast<const bf16x8*>(&Xs[kx * 512 + rdo]);
            wreg[38 + kx] = *reinterpret_cast<const bf16x8*>(&Xs[1024 + kx * 512 + rdo]);
        }
    }

    // dense tap state (w0/w1): Wd parity buffers (2-step prefetch) + fp32 acc
    f32x4 wdE[2], wdO[2], dacc[2];
    const float* wdp_e = Wd;
    const float* wdp_o = Wd;
    if (w < 2) {
        const int wco = w * 32 + quad * 4;
#pragma unroll
        for (int mt = 0; mt < 2; ++mt) {
            float4 a0 = *reinterpret_cast<const float4*>(Wd + 0 * 64 + wco + mt * 16);
            float4 a1 = *reinterpret_cast<const float4*>(Wd + 1 * 64 + wco + mt * 16);
            wdO[mt][0] = a0.x; wdO[mt][1] = a0.y; wdO[mt][2] = a0.z; wdO[mt][3] = a0.w;
            wdE[mt][0] = a1.x; wdE[mt][1] = a1.y; wdE[mt][2] = a1.z; wdE[mt][3] = a1.w;
            dacc[mt] = (f32x4)(0.0f);
        }
        wdp_o = Wd + 2 * 64 + wco;   // next odd-parity t4 = 2
        wdp_e = Wd + 3 * 64 + wco;   // next even-parity t4 = 3
    }
    __syncthreads();

    const unsigned short* xp0 = Xs + 2 * 1024 + rdo;   // even prefetch target
    const unsigned short* xp1 = Xs + 3 * 1024 + rdo;   // odd

    const int wro1 = (w * 8 + (quad >> 1)) * 128 + l15 * 8 + (quad & 1) * 4;
    const int wro4 = 8192 + (w * 4 + (quad >> 1)) * 128 + l15 * 8 + (quad & 1) * 4;
    const int wro2 = 2048 + ((w - 2) * 8 + (quad >> 1)) * 128 + l15 * 8 + (quad & 1) * 4;
    const int wro3 = 6144 + ((w - 6) * 8 + (quad >> 1)) * 128 + l15 * 8 + (quad & 1) * 4;

#define PACKMK(ACC_MT)                                                             \
    ushort2 lo = pk2(fmaxf((ACC_MT)[0], 0.f), fmaxf((ACC_MT)[1], 0.f));            \
    ushort2 hi = pk2(fmaxf((ACC_MT)[2], 0.f), fmaxf((ACC_MT)[3], 0.f));            \
    ushort4 o; o.x = lo.x; o.y = lo.y; o.z = hi.x; o.w = hi.y;

#define STEP(TAU_, RP_, WP_, XAB, XPP, WDB, WDP)                                   \
    {                                                                              \
        const int tau_ = (TAU_);                                                   \
        const unsigned short* RB = &hall[RP_][0];                                  \
        unsigned short* WB = &hall[WP_][0];                                        \
        if (w < 2) {                                                               \
            if ((unsigned)tau_ < TT) { /* L1 */                                    \
                f32x4 acc[4];                                                      \
                _Pragma("unroll")                                                  \
                for (int mt = 0; mt < 4; ++mt)                                     \
                    acc[mt] = __builtin_amdgcn_mfma_f32_16x16x32_bf16(             \
                        wreg[16 + mt], wreg[(XAB) + 0], bvv[mt], 0, 0, 0);         \
                _Pragma("unroll")                                                  \
                for (int mt = 0; mt < 4; ++mt)                                     \
                    acc[mt] = __builtin_amdgcn_mfma_f32_16x16x32_bf16(             \
                        wreg[20 + mt], wreg[(XAB) + 1], acc[mt], 0, 0, 0);         \
                if (tau_ + 2 < TT) {                                               \
                    wreg[(XAB) + 0] = *reinterpret_cast<const bf16x8*>(XPP);       \
                    wreg[(XAB) + 1] = *reinterpret_cast<const bf16x8*>(XPP + 512); \
                    XPP += 2048;                                                   \
                }                                                                  \
                _Pragma("unroll")                                                  \
                for (int kc = 0; kc < 4; ++kc) {                                   \
                    bf16x8 af = *reinterpret_cast<const bf16x8*>(&RB[rdo + kc * 512]); \
                    _Pragma("unroll")                                              \
                    for (int mt = 0; mt < 4; ++mt)                                 \
                        acc[mt] = __builtin_amdgcn_mfma_f32_16x16x32_bf16(         \
                            wreg[kc * 4 + mt], af, acc[mt], 0, 0, 0);              \
                }                                                                  \
                _Pragma("unroll")                                                  \
                for (int mt = 0; mt < 4; ++mt) {                                   \
                    PACKMK(acc[mt])                                                \
                    *reinterpret_cast<ushort4*>(&WB[wro1 + mt * 256]) = o;         \
                }                                                                  \
            }                                                                      \
            if ((unsigned)(tau_ - 3) < TT) { /* L4 + dense tap */                  \
                f32x4 acc[2];                                                      \
                {                                                                  \
                    bf16x8 af0 = *reinterpret_cast<const bf16x8*>(&RB[6144 + rdo]); \
                    _Pragma("unroll")                                              \
                    for (int mt = 0; mt < 2; ++mt)                                 \
                        acc[mt] = __builtin_amdgcn_mfma_f32_16x16x32_bf16(         \
                            wreg[28 + mt], af0, bvv[4 + mt], 0, 0, 0);             \
                }                                                                  \
                _Pragma("unroll")                                                  \
                for (int kx = 1; kx < 4; ++kx) {                                   \
                    bf16x8 af = *reinterpret_cast<const bf16x8*>(&RB[6144 + rdo + kx * 512]); \
                    _Pragma("unroll")                                              \
                    for (int mt = 0; mt < 2; ++mt)                                 \
                        acc[mt] = __builtin_amdgcn_mfma_f32_16x16x32_bf16(         \
                            wreg[28 + kx * 2 + mt], af, acc[mt], 0, 0, 0);         \
                }                                                                  \
                _Pragma("unroll")                                                  \
                for (int kc = 0; kc < 2; ++kc) {                                   \
                    bf16x8 af = *reinterpret_cast<const bf16x8*>(&RB[8192 + rdo + kc * 512]); \
                    _Pragma("unroll")                                              \
                    for (int mt = 0; mt < 2; ++mt)                                 \
                        acc[mt] = __builtin_amdgcn_mfma_f32_16x16x32_bf16(         \
                            wreg[24 + kc * 2 + mt], af, acc[mt], 0, 0, 0);         \
                }                                                                  \
                _Pragma("unroll")                                                  \
                for (int mt = 0; mt < 2; ++mt) {                                   \
                    float r0 = fmaxf(acc[mt][0], 0.f), r1 = fmaxf(acc[mt][1], 0.f); \
                    float r2 = fmaxf(acc[mt][2], 0.f), r3 = fmaxf(acc[mt][3], 0.f); \
                    ushort2 lo = pk2(r0, r1); ushort2 hi = pk2(r2, r3);            \
                    ushort4 o; o.x = lo.x; o.y = lo.y; o.z = hi.x; o.w = hi.y;     \
                    *reinterpret_cast<ushort4*>(&WB[wro4 + mt * 256]) = o;         \
                    dacc[mt][0] += r0 * WDB[mt][0]; dacc[mt][1] += r1 * WDB[mt][1]; \
                    dacc[mt][2] += r2 * WDB[mt][2]; dacc[mt][3] += r3 * WDB[mt][3]; \
                }                                                                  \
                if ((tau_ - 3) + 2 < TT) {                                         \
                    float4 a0 = *reinterpret_cast<const float4*>(WDP);             \
                    float4 a1 = *reinterpret_cast<const float4*>(WDP + 16);        \
                    WDB[0][0] = a0.x; WDB[0][1] = a0.y; WDB[0][2] = a0.z; WDB[0][3] = a0.w; \
                    WDB[1][0] = a1.x; WDB[1][1] = a1.y; WDB[1][2] = a1.z; WDB[1][3] = a1.w; \
                    WDP += 128;                                                    \
                }                                                                  \
            }                                                                      \
        } else if (w < 6) {                                                        \
            if ((unsigned)(tau_ - 1) < TT) { /* L2 */                              \
                f32x4 acc[4];                                                      \
                {                                                                  \
                    bf16x8 af0 = *reinterpret_cast<const bf16x8*>(&RB[rdo]);       \
                    _Pragma("unroll")                                              \
                    for (int mt = 0; mt < 4; ++mt)                                 \
                        acc[mt] = __builtin_amdgcn_mfma_f32_16x16x32_bf16(         \
                            wreg[32 + mt], af0, bvv[mt], 0, 0, 0);                 \
                }                                                                  \
                _Pragma("unroll")                                                  \
                for (int kx = 1; kx < 4; ++kx) {                                   \
                    bf16x8 af = *reinterpret_cast<const bf16x8*>(&RB[rdo + kx * 512]); \
                    _Pragma("unroll")                                              \
                    for (int mt = 0; mt < 4; ++mt)                                 \
                        acc[mt] = __builtin_amdgcn_mfma_f32_16x16x32_bf16(         \
                            wreg[32 + kx * 4 + mt], af, acc[mt], 0, 0, 0);         \
                }                                                                  \
                _Pragma("unroll")                                                  \
                for (int kc = 0; kc < 8; ++kc) {                                   \
                    bf16x8 af = *reinterpret_cast<const bf16x8*>(&RB[2048 + rdo + kc * 512]); \
                    _Pragma("unroll")                                              \
                    for (int mt = 0; mt < 4; ++mt)                                 \
                        acc[mt] = __builtin_amdgcn_mfma_f32_16x16x32_bf16(         \
                            wreg[kc * 4 + mt], af, acc[mt], 0, 0, 0);              \
                }                                                                  \
                _Pragma("unroll")                                                  \
                for (int mt = 0; mt < 4; ++mt) {                                   \
                    PACKMK(acc[mt])                                                \
                    *reinterpret_cast<ushort4*>(&WB[wro2 + mt * 256]) = o;         \
                }                                                                  \
            }                                                                      \
        } else {                                                                   \
            if ((unsigned)(tau_ - 2) < TT) { /* L3 */                              \
                f32x4 acc[4];                                                      \
                {                                                                  \
                    bf16x8 af0 = *reinterpret_cast<const bf16x8*>(&RB[2048 + rdo]); \
                    _Pragma("unroll")                                              \
                    for (int mt = 0; mt < 4; ++mt)                                 \
                        acc[mt] = __builtin_amdgcn_mfma_f32_16x16x32_bf16(         \
                            wreg[16 + mt], af0, bvv[mt], 0, 0, 0);                 \
                }                                                                  \
                _Pragma("unroll")                                                  \
                for (int kx = 1; kx < 8; ++kx) {                                   \
                    bf16x8 af = *reinterpret_cast<const bf16x8*>(&RB[2048 + rdo + kx * 512]); \
                    _Pragma("unroll")                                              \
                    for (int mt = 0; mt < 4; ++mt)                                 \
                        acc[mt] = __builtin_amdgcn_mfma_f32_16x16x32_bf16(         \
                            wreg[16 + kx * 4 + mt], af, acc[mt], 0, 0, 0);         \
                }                                                                  \
                _Pragma("unroll")                                                  \
                for (int kc = 0; kc < 4; ++kc) {                                   \
                    bf16x8 af = *reinterpret_cast<const bf16x8*>(&RB[6144 + rdo + kc * 512]); \
                    _Pragma("unroll")                                              \
                    for (int mt = 0; mt < 4; ++mt)                                 \
                        acc[mt] = __builtin_amdgcn_mfma_f32_16x16x32_bf16(         \
                            wreg[kc * 4 + mt], af, acc[mt], 0, 0, 0);              \
                }                                                                  \
                _Pragma("unroll")                                                  \
                for (int mt = 0; mt < 4; ++mt) {                                   \
                    PACKMK(acc[mt])                                                \
                    *reinterpret_cast<ushort4*>(&WB[wro3 + mt * 256]) = o;         \
                }                                                                  \
            }                                                                      \
        }                                                                          \
        __builtin_amdgcn_s_waitcnt(0xC07F);                                        \
        __builtin_amdgcn_s_barrier();                                              \
    }

#pragma unroll 1
    for (int tau = 0; tau < TT + 3; tau += 2) {
        STEP(tau, 0, 1, 36, xp0, wdE, wdp_e)
        STEP(tau + 1, 1, 0, 38, xp1, wdO, wdp_o)
    }
#undef STEP
#undef PACKMK

    // ---- dense epilogue: reduce dacc across (w<2) x quads -> out[s*16+b] ----
    float* red = reinterpret_cast<float*>(&hall[0][0]);
    if (w < 2) {
        float p = dacc[0][0] + dacc[0][1] + dacc[0][2] + dacc[0][3]
                + dacc[1][0] + dacc[1][1] + dacc[1][2] + dacc[1][3];
        red[l15 * 8 + w * 4 + quad] = p;
    }
    __syncthreads();
    if (tid < 16) {
        float sum = 0.f;
#pragma unroll
        for (int j = 0; j < 8; ++j) sum += red[tid * 8 + j];
        out[s * 16 + tid] = sum + bd[0];
    }
}

extern "C" void kernel_launch(void* const* d_in, const int* in_sizes, int n_in,
                              void* d_out, int out_size, void* d_ws, size_t ws_size,
                              hipStream_t stream) {
    (void)in_sizes; (void)n_in; (void)out_size; (void)ws_size;
    const float* x   = (const float*)d_in[0];
    const float* Wx1 = (const float*)d_in[1];
    const float* Wh1 = (const float*)d_in[2];
    const float* b1  = (const float*)d_in[3];
    const float* Wx2 = (const float*)d_in[4];
    const float* Wh2 = (const float*)d_in[5];
    const float* b2  = (const float*)d_in[6];
    const float* Wx3 = (const float*)d_in[7];
    const float* Wh3 = (const float*)d_in[8];
    const float* b3  = (const float*)d_in[9];
    const float* Wx4 = (const float*)d_in[10];
    const float* Wh4 = (const float*)d_in[11];
    const float* b4  = (const float*)d_in[12];
    const float* Wd  = (const float*)d_in[13];
    const float* bd  = (const float*)d_in[14];
    float* out = (float*)d_out;

    char* ws = (char*)d_ws;
    unsigned short* xbT = (unsigned short*)(ws);   // 16.8M

    cvt_tile<<<8192, 256, 0, stream>>>(x, xbT);

    rnn4<<<32, 512, 0, stream>>>(xbT, Wx1, Wh1, b1, Wx2, Wh2, b2,
                                 Wx3, Wh3, b3, Wx4, Wh4, b4, Wd, bd, out);
}

// Round 17
// 422.384 us; speedup vs baseline: 1.4830x; 1.4830x over previous
//
#include <hip/hip_runtime.h>
#include <hip/hip_bf16.h>

#define BB 512
#define TT 256

typedef __attribute__((ext_vector_type(8))) short bf16x8;
typedef __attribute__((ext_vector_type(4))) float f32x4;

__device__ __forceinline__ unsigned short f2b(float f) {
    union { float f; unsigned u; } v; v.f = f;
    unsigned r = v.u + 0x7FFFu + ((v.u >> 16) & 1u);
    return (unsigned short)(r >> 16);
}
__device__ __forceinline__ float b2f(unsigned short h) {
    union { unsigned u; float f; } v; v.u = ((unsigned)h) << 16;
    return v.f;
}
__device__ __forceinline__ ushort2 pk2(float a, float b) {
    __hip_bfloat162 h = __float22bfloat162_rn(float2{a, b});
    union { __hip_bfloat162 h; ushort2 u; } v; v.h = h; return v.u;
}

// B-layout per (s,t): 16-batch x K shorts, addr(b,k) = (k>>3)*128 + b*8 + (k&7).
// B-frag kc = one b128 at kc*512 + rdo (rdo = quad*128 + l15*8);
// D-tile mt write = ushort4 at wro + mt*256.

// ---------------- fp32 x -> bf16 B-layout tiles ----------------
__global__ __launch_bounds__(256) void cvt_tile(const float* __restrict__ x,
                                                unsigned short* __restrict__ xb) {
    const int blk = blockIdx.x;            // s*256 + t
    const int s = blk >> 8, t = blk & 255;
    const int tid = threadIdx.x;
    const int b = (tid >> 1) & 15;
    const int f0 = (tid >> 5) * 8 + (tid & 1) * 4;
    float4 v = *reinterpret_cast<const float4*>(
        &x[(((size_t)(s * 16 + b) * TT) + t) * 64 + f0]);
    ushort2 lo = pk2(v.x, v.y), hi = pk2(v.z, v.w);
    ushort4 o; o.x = lo.x; o.y = lo.y; o.z = hi.x; o.w = hi.y;
    *reinterpret_cast<ushort4*>(&xb[(size_t)blk * 1024 + tid * 4]) = o;
}

// ---------------- 4-layer skewed fused RNN, wave-specialized ----------------
// EXACT round-15 winner (325 us). 8 waves: w0,w1 = L1+L4; w2-5 = L2; w6,7 =
// L3. wreg[48] weights; wreg[36..39] = w0/w1 x parity prefetch. Bias enters
// as C operand of first input-MFMA. L4 stores h4 to global from pack regs.
// NOTE (r16 lesson): w0/w1 have NO register headroom — do not add state.
__global__ __launch_bounds__(512) __attribute__((amdgpu_waves_per_eu(2, 2))) void rnn4(
    const unsigned short* __restrict__ Xb,
    const float* __restrict__ Wx1, const float* __restrict__ Wh1, const float* __restrict__ b1,
    const float* __restrict__ Wx2, const float* __restrict__ Wh2, const float* __restrict__ b2,
    const float* __restrict__ Wx3, const float* __restrict__ Wh3, const float* __restrict__ b3,
    const float* __restrict__ Wx4, const float* __restrict__ Wh4, const float* __restrict__ b4,
    unsigned short* __restrict__ H4) {
    const int tid = threadIdx.x;
    const int s = blockIdx.x;
    const int w = tid >> 6;
    const int lane = tid & 63;
    const int l15 = lane & 15;
    const int quad = lane >> 4;
    const int rdo = quad * 128 + l15 * 8;

    // LDS: h1[0,2048) h2[2048,6144) h3[6144,8192) h4[8192,9216) per parity
    __shared__ __align__(16) unsigned short hall[2][9216];

    bf16x8 wreg[48];
    f32x4 bvv[6];

#define LOADW(BASE, WP, H_, CB, KC_, MT_)                                          \
    _Pragma("unroll")                                                              \
    for (int mt = 0; mt < MT_; ++mt) {                                             \
        int m = (CB) + mt * 16 + l15;                                              \
        _Pragma("unroll")                                                          \
        for (int kc = 0; kc < KC_; ++kc)                                           \
            _Pragma("unroll")                                                      \
            for (int j = 0; j < 8; ++j)                                            \
                wreg[(BASE) + kc * MT_ + mt][j] =                                  \
                    (short)f2b(WP[(kc * 32 + quad * 8 + j) * H_ + m]);             \
    }
#define LOADBF(OFF, BP, CB, MT_)                                                   \
    _Pragma("unroll")                                                              \
    for (int mt = 0; mt < MT_; ++mt) {                                             \
        float4 t4v = *reinterpret_cast<const float4*>((BP) + (CB) + mt * 16 + quad * 4); \
        bvv[(OFF) + mt][0] = t4v.x; bvv[(OFF) + mt][1] = t4v.y;                    \
        bvv[(OFF) + mt][2] = t4v.z; bvv[(OFF) + mt][3] = t4v.w;                    \
    }

    if (w < 2) {
        LOADW(0,  Wh1, 128, w * 64, 4, 4)
        LOADW(16, Wx1, 128, w * 64, 2, 4)
        LOADW(24, Wh4, 64,  w * 32, 2, 2)
        LOADW(28, Wx4, 64,  w * 32, 4, 2)
        LOADBF(0, b1, w * 64, 4)
        LOADBF(4, b4, w * 32, 2)
    } else if (w < 6) {
        LOADW(0,  Wh2, 256, (w - 2) * 64, 8, 4)
        LOADW(32, Wx2, 256, (w - 2) * 64, 4, 4)
        LOADBF(0, b2, (w - 2) * 64, 4)
    } else {
        LOADW(0,  Wh3, 128, (w - 6) * 64, 4, 4)
        LOADW(16, Wx3, 128, (w - 6) * 64, 8, 4)
        LOADBF(0, b3, (w - 6) * 64, 4)
    }
#undef LOADW
#undef LOADBF

    for (int i = tid; i < 2 * 9216; i += 512) (&hall[0][0])[i] = 0;

    const unsigned short* Xs = Xb + (size_t)s * TT * 1024;
    unsigned short* H4s = H4 + (size_t)s * TT * 1024;

    // x parity prefetch into wreg[36..39]: [36,37] even t, [38,39] odd t
    if (w < 2) {
#pragma unroll
        for (int kx = 0; kx < 2; ++kx) {
            wreg[36 + kx] = *reinterpret_cast<const bf16x8*>(&Xs[kx * 512 + rdo]);
            wreg[38 + kx] = *reinterpret_cast<const bf16x8*>(&Xs[1024 + kx * 512 + rdo]);
        }
    }
    __syncthreads();

    const unsigned short* xp0 = Xs + 2 * 1024 + rdo;   // even prefetch target
    const unsigned short* xp1 = Xs + 3 * 1024 + rdo;   // odd

    const int wro1 = (w * 8 + (quad >> 1)) * 128 + l15 * 8 + (quad & 1) * 4;
    const int wro4 = 8192 + (w * 4 + (quad >> 1)) * 128 + l15 * 8 + (quad & 1) * 4;
    const int wro2 = 2048 + ((w - 2) * 8 + (quad >> 1)) * 128 + l15 * 8 + (quad & 1) * 4;
    const int wro3 = 6144 + ((w - 6) * 8 + (quad >> 1)) * 128 + l15 * 8 + (quad & 1) * 4;

    // L4 direct global store: even-macro (tau even) stores t4 = tau-3 (odd);
    // odd-macro stores even t4. g-offset = wro4 - 8192 (+ mt*256).
    unsigned short* op_e = H4s + 1024 + (wro4 - 8192);  // first even-macro t4 = 1
    unsigned short* op_o = H4s + (wro4 - 8192);         // first odd-macro  t4 = 0

#define PACKMK(ACC_MT)                                                             \
    ushort2 lo = pk2(fmaxf((ACC_MT)[0], 0.f), fmaxf((ACC_MT)[1], 0.f));            \
    ushort2 hi = pk2(fmaxf((ACC_MT)[2], 0.f), fmaxf((ACC_MT)[3], 0.f));            \
    ushort4 o; o.x = lo.x; o.y = lo.y; o.z = hi.x; o.w = hi.y;

#define STEP(TAU_, RP_, WP_, XAB, XPP, OPP)                                        \
    {                                                                              \
        const int tau_ = (TAU_);                                                   \
        const unsigned short* RB = &hall[RP_][0];                                  \
        unsigned short* WB = &hall[WP_][0];                                        \
        if (w < 2) {                                                               \
            if ((unsigned)tau_ < TT) { /* L1 */                                    \
                f32x4 acc[4];                                                      \
                _Pragma("unroll")                                                  \
                for (int mt = 0; mt < 4; ++mt)                                     \
                    acc[mt] = __builtin_amdgcn_mfma_f32_16x16x32_bf16(             \
                        wreg[16 + mt], wreg[(XAB) + 0], bvv[mt], 0, 0, 0);         \
                _Pragma("unroll")                                                  \
                for (int mt = 0; mt < 4; ++mt)                                     \
                    acc[mt] = __builtin_amdgcn_mfma_f32_16x16x32_bf16(             \
                        wreg[20 + mt], wreg[(XAB) + 1], acc[mt], 0, 0, 0);         \
                if (tau_ + 2 < TT) {                                               \
                    wreg[(XAB) + 0] = *reinterpret_cast<const bf16x8*>(XPP);       \
                    wreg[(XAB) + 1] = *reinterpret_cast<const bf16x8*>(XPP + 512); \
                    XPP += 2048;                                                   \
                }                                                                  \
                _Pragma("unroll")                                                  \
                for (int kc = 0; kc < 4; ++kc) {                                   \
                    bf16x8 af = *reinterpret_cast<const bf16x8*>(&RB[rdo + kc * 512]); \
                    _Pragma("unroll")                                              \
                    for (int mt = 0; mt < 4; ++mt)                                 \
                        acc[mt] = __builtin_amdgcn_mfma_f32_16x16x32_bf16(         \
                            wreg[kc * 4 + mt], af, acc[mt], 0, 0, 0);              \
                }                                                                  \
                _Pragma("unroll")                                                  \
                for (int mt = 0; mt < 4; ++mt) {                                   \
                    PACKMK(acc[mt])                                                \
                    *reinterpret_cast<ushort4*>(&WB[wro1 + mt * 256]) = o;         \
                }                                                                  \
            }                                                                      \
            if ((unsigned)(tau_ - 3) < TT) { /* L4 */                              \
                f32x4 acc[2];                                                      \
                {                                                                  \
                    bf16x8 af0 = *reinterpret_cast<const bf16x8*>(&RB[6144 + rdo]); \
                    _Pragma("unroll")                                              \
                    for (int mt = 0; mt < 2; ++mt)                                 \
                        acc[mt] = __builtin_amdgcn_mfma_f32_16x16x32_bf16(         \
                            wreg[28 + mt], af0, bvv[4 + mt], 0, 0, 0);             \
                }                                                                  \
                _Pragma("unroll")                                                  \
                for (int kx = 1; kx < 4; ++kx) {                                   \
                    bf16x8 af = *reinterpret_cast<const bf16x8*>(&RB[6144 + rdo + kx * 512]); \
                    _Pragma("unroll")                                              \
                    for (int mt = 0; mt < 2; ++mt)                                 \
                        acc[mt] = __builtin_amdgcn_mfma_f32_16x16x32_bf16(         \
                            wreg[28 + kx * 2 + mt], af, acc[mt], 0, 0, 0);         \
                }                                                                  \
                _Pragma("unroll")                                                  \
                for (int kc = 0; kc < 2; ++kc) {                                   \
                    bf16x8 af = *reinterpret_cast<const bf16x8*>(&RB[8192 + rdo + kc * 512]); \
                    _Pragma("unroll")                                              \
                    for (int mt = 0; mt < 2; ++mt)                                 \
                        acc[mt] = __builtin_amdgcn_mfma_f32_16x16x32_bf16(         \
                            wreg[24 + kc * 2 + mt], af, acc[mt], 0, 0, 0);         \
                }                                                                  \
                _Pragma("unroll")                                                  \
                for (int mt = 0; mt < 2; ++mt) {                                   \
                    PACKMK(acc[mt])                                                \
                    *reinterpret_cast<ushort4*>(&WB[wro4 + mt * 256]) = o;         \
                    *reinterpret_cast<ushort4*>(OPP + mt * 256) = o;               \
                }                                                                  \
                OPP += 2048;                                                       \
            }                                                                      \
        } else if (w < 6) {                                                        \
            if ((unsigned)(tau_ - 1) < TT) { /* L2 */                              \
                f32x4 acc[4];                                                      \
                {                                                                  \
                    bf16x8 af0 = *reinterpret_cast<const bf16x8*>(&RB[rdo]);       \
                    _Pragma("unroll")                                              \
                    for (int mt = 0; mt < 4; ++mt)                                 \
                        acc[mt] = __builtin_amdgcn_mfma_f32_16x16x32_bf16(         \
                            wreg[32 + mt], af0, bvv[mt], 0, 0, 0);                 \
                }                                                                  \
                _Pragma("unroll")                                                  \
                for (int kx = 1; kx < 4; ++kx) {                                   \
                    bf16x8 af = *reinterpret_cast<const bf16x8*>(&RB[rdo + kx * 512]); \
                    _Pragma("unroll")                                              \
                    for (int mt = 0; mt < 4; ++mt)                                 \
                        acc[mt] = __builtin_amdgcn_mfma_f32_16x16x32_bf16(         \
                            wreg[32 + kx * 4 + mt], af, acc[mt], 0, 0, 0);         \
                }                                                                  \
                _Pragma("unroll")                                                  \
                for (int kc = 0; kc < 8; ++kc) {                                   \
                    bf16x8 af = *reinterpret_cast<const bf16x8*>(&RB[2048 + rdo + kc * 512]); \
                    _Pragma("unroll")                                              \
                    for (int mt = 0; mt < 4; ++mt)                                 \
                        acc[mt] = __builtin_amdgcn_mfma_f32_16x16x32_bf16(         \
                            wreg[kc * 4 + mt], af, acc[mt], 0, 0, 0);              \
                }                                                                  \
                _Pragma("unroll")                                                  \
                for (int mt = 0; mt < 4; ++mt) {                                   \
                    PACKMK(acc[mt])                                                \
                    *reinterpret_cast<ushort4*>(&WB[wro2 + mt * 256]) = o;         \
                }                                                                  \
            }                                                                      \
        } else {                                                                   \
            if ((unsigned)(tau_ - 2) < TT) { /* L3 */                              \
                f32x4 acc[4];                                                      \
                {                                                                  \
                    bf16x8 af0 = *reinterpret_cast<const bf16x8*>(&RB[2048 + rdo]); \
                    _Pragma("unroll")                                              \
                    for (int mt = 0; mt < 4; ++mt)                                 \
                        acc[mt] = __builtin_amdgcn_mfma_f32_16x16x32_bf16(         \
                            wreg[16 + mt], af0, bvv[mt], 0, 0, 0);                 \
                }                                                                  \
                _Pragma("unroll")                                                  \
                for (int kx = 1; kx < 8; ++kx) {                                   \
                    bf16x8 af = *reinterpret_cast<const bf16x8*>(&RB[2048 + rdo + kx * 512]); \
                    _Pragma("unroll")                                              \
                    for (int mt = 0; mt < 4; ++mt)                                 \
                        acc[mt] = __builtin_amdgcn_mfma_f32_16x16x32_bf16(         \
                            wreg[16 + kx * 4 + mt], af, acc[mt], 0, 0, 0);         \
                }                                                                  \
                _Pragma("unroll")                                                  \
                for (int kc = 0; kc < 4; ++kc) {                                   \
                    bf16x8 af = *reinterpret_cast<const bf16x8*>(&RB[6144 + rdo + kc * 512]); \
                    _Pragma("unroll")                                              \
                    for (int mt = 0; mt < 4; ++mt)                                 \
                        acc[mt] = __builtin_amdgcn_mfma_f32_16x16x32_bf16(         \
                            wreg[kc * 4 + mt], af, acc[mt], 0, 0, 0);              \
                }                                                                  \
                _Pragma("unroll")                                                  \
                for (int mt = 0; mt < 4; ++mt) {                                   \
                    PACKMK(acc[mt])                                                \
                    *reinterpret_cast<ushort4*>(&WB[wro3 + mt * 256]) = o;         \
                }                                                                  \
            }                                                                      \
        }                                                                          \
        __builtin_amdgcn_s_waitcnt(0xC07F);                                        \
        __builtin_amdgcn_s_barrier();                                              \
    }

#pragma unroll 1
    for (int tau = 0; tau < TT + 3; tau += 2) {
        STEP(tau, 0, 1, 36, xp0, op_e)
        STEP(tau + 1, 1, 0, 38, xp1, op_o)
    }
#undef STEP
#undef PACKMK
}

// ---------------- final dense, gridded: 256 blocks = 32 s x 8 t-chunks ------
// Each block reduces 32 timesteps of Ht (B-layout, K=64) and atomicAdds 16
// per-batch partials into out. tc==0 blocks add bd. out pre-zeroed by memset.
__global__ __launch_bounds__(256) void dense_part(const unsigned short* __restrict__ Ht,
                                                  const float* __restrict__ Wd,
                                                  const float* __restrict__ bd,
                                                  float* __restrict__ out) {
    __shared__ float red[16][17];
    const int s = blockIdx.x >> 3;
    const int tc = blockIdx.x & 7;
    const int tid = threadIdx.x;
    const int b = (tid >> 1) & 15;
    const int kbase = (tid >> 5) * 8 + (tid & 1) * 4;
    const unsigned short* base = Ht + ((size_t)s * TT + tc * 32) * 1024 + tid * 4;
    float acc = 0.f;
    for (int t = 0; t < 32; ++t) {
        ushort4 v = *reinterpret_cast<const ushort4*>(base + (size_t)t * 1024);
        const float* wd = &Wd[(tc * 32 + t) * 64 + kbase];
        acc += b2f(v.x) * wd[0] + b2f(v.y) * wd[1] + b2f(v.z) * wd[2] + b2f(v.w) * wd[3];
    }
    red[b][(tid >> 5) * 2 + (tid & 1)] = acc;
    __syncthreads();
    if (tid < 16) {
        float sum = 0.f;
#pragma unroll
        for (int j = 0; j < 16; ++j) sum += red[tid][j];
        if (tc == 0) sum += bd[0];
        atomicAdd(&out[s * 16 + tid], sum);
    }
}

extern "C" void kernel_launch(void* const* d_in, const int* in_sizes, int n_in,
                              void* d_out, int out_size, void* d_ws, size_t ws_size,
                              hipStream_t stream) {
    (void)in_sizes; (void)n_in; (void)ws_size;
    const float* x   = (const float*)d_in[0];
    const float* Wx1 = (const float*)d_in[1];
    const float* Wh1 = (const float*)d_in[2];
    const float* b1  = (const float*)d_in[3];
    const float* Wx2 = (const float*)d_in[4];
    const float* Wh2 = (const float*)d_in[5];
    const float* b2  = (const float*)d_in[6];
    const float* Wx3 = (const float*)d_in[7];
    const float* Wh3 = (const float*)d_in[8];
    const float* b3  = (const float*)d_in[9];
    const float* Wx4 = (const float*)d_in[10];
    const float* Wh4 = (const float*)d_in[11];
    const float* b4  = (const float*)d_in[12];
    const float* Wd  = (const float*)d_in[13];
    const float* bd  = (const float*)d_in[14];
    float* out = (float*)d_out;

    char* ws = (char*)d_ws;
    unsigned short* xbT = (unsigned short*)(ws);             // 16.8M
    unsigned short* H4  = (unsigned short*)(ws + 16777216);  // 16.8M

    hipMemsetAsync(out, 0, (size_t)out_size * sizeof(float), stream);

    cvt_tile<<<8192, 256, 0, stream>>>(x, xbT);

    rnn4<<<32, 512, 0, stream>>>(xbT, Wx1, Wh1, b1, Wx2, Wh2, b2,
                                 Wx3, Wh3, b3, Wx4, Wh4, b4, H4);

    dense_part<<<256, 256, 0, stream>>>(H4, Wd, bd, out);
}

// Round 18
// 421.909 us; speedup vs baseline: 1.4846x; 1.0011x over previous
//
#include <hip/hip_runtime.h>
#include <hip/hip_bf16.h>

#define BB 512
#define TT 256

typedef __attribute__((ext_vector_type(8))) short bf16x8;
typedef __attribute__((ext_vector_type(4))) float f32x4;

__device__ __forceinline__ unsigned short f2b(float f) {
    union { float f; unsigned u; } v; v.f = f;
    unsigned r = v.u + 0x7FFFu + ((v.u >> 16) & 1u);
    return (unsigned short)(r >> 16);
}
__device__ __forceinline__ float b2f(unsigned short h) {
    union { unsigned u; float f; } v; v.u = ((unsigned)h) << 16;
    return v.f;
}
__device__ __forceinline__ ushort2 pk2(float a, float b) {
    __hip_bfloat162 h = __float22bfloat162_rn(float2{a, b});
    union { __hip_bfloat162 h; ushort2 u; } v; v.h = h; return v.u;
}

// B-layout per (s,t): 16-batch x K shorts, addr(b,k) = (k>>3)*128 + b*8 + (k&7).
// B-frag kc = one b128 at kc*512 + rdo (rdo = quad*128 + l15*8);
// D-tile mt write = ushort4 at wro + mt*256.

// ---------------- fp32 x -> bf16 B-layout tiles (4 t per block) ----------------
__global__ __launch_bounds__(256) void cvt_tile4(const float* __restrict__ x,
                                                 unsigned short* __restrict__ xb) {
    const int s = blockIdx.x >> 6;          // 0..31
    const int tg = blockIdx.x & 63;         // 0..63, 4 t's each
    const int tid = threadIdx.x;
    const int b = (tid >> 1) & 15;
    const int f0 = (tid >> 5) * 8 + (tid & 1) * 4;
    const float* xrow = &x[(((size_t)(s * 16 + b) * TT) + tg * 4) * 64 + f0];
    unsigned short* ob = &xb[((size_t)(s * TT) + tg * 4) * 1024 + tid * 4];
#pragma unroll
    for (int tt = 0; tt < 4; ++tt) {
        float4 v = *reinterpret_cast<const float4*>(xrow + tt * 64);
        ushort2 lo = pk2(v.x, v.y), hi = pk2(v.z, v.w);
        ushort4 o; o.x = lo.x; o.y = lo.y; o.z = hi.x; o.w = hi.y;
        *reinterpret_cast<ushort4*>(ob + tt * 1024) = o;
    }
}

// ---------------- 4-layer skewed fused RNN, wave-specialized ----------------
// EXACT round-15/17 winner hot loop. 8 waves: w0,w1 = L1+L4; w2-5 = L2;
// w6,7 = L3. wreg[48] weights; wreg[36..39] = w0/w1 x parity prefetch. Bias
// enters as C operand of first input-MFMA. L4 stores h4 to global from pack
// regs. w2-5 get s_setprio(1) (heavy waves: narrow barrier-arrival spread).
// NOTE (r16 lesson): w0/w1 have NO register headroom — do not add state.
__global__ __launch_bounds__(512) __attribute__((amdgpu_waves_per_eu(2, 2))) void rnn4(
    const unsigned short* __restrict__ Xb,
    const float* __restrict__ Wx1, const float* __restrict__ Wh1, const float* __restrict__ b1,
    const float* __restrict__ Wx2, const float* __restrict__ Wh2, const float* __restrict__ b2,
    const float* __restrict__ Wx3, const float* __restrict__ Wh3, const float* __restrict__ b3,
    const float* __restrict__ Wx4, const float* __restrict__ Wh4, const float* __restrict__ b4,
    unsigned short* __restrict__ H4) {
    const int tid = threadIdx.x;
    const int s = blockIdx.x;
    const int w = tid >> 6;
    const int lane = tid & 63;
    const int l15 = lane & 15;
    const int quad = lane >> 4;
    const int rdo = quad * 128 + l15 * 8;

    // LDS: h1[0,2048) h2[2048,6144) h3[6144,8192) h4[8192,9216) per parity
    __shared__ __align__(16) unsigned short hall[2][9216];

    bf16x8 wreg[48];
    f32x4 bvv[6];

#define LOADW(BASE, WP, H_, CB, KC_, MT_)                                          \
    _Pragma("unroll")                                                              \
    for (int mt = 0; mt < MT_; ++mt) {                                             \
        int m = (CB) + mt * 16 + l15;                                              \
        _Pragma("unroll")                                                          \
        for (int kc = 0; kc < KC_; ++kc)                                           \
            _Pragma("unroll")                                                      \
            for (int j = 0; j < 8; ++j)                                            \
                wreg[(BASE) + kc * MT_ + mt][j] =                                  \
                    (short)f2b(WP[(kc * 32 + quad * 8 + j) * H_ + m]);             \
    }
#define LOADBF(OFF, BP, CB, MT_)                                                   \
    _Pragma("unroll")                                                              \
    for (int mt = 0; mt < MT_; ++mt) {                                             \
        float4 t4v = *reinterpret_cast<const float4*>((BP) + (CB) + mt * 16 + quad * 4); \
        bvv[(OFF) + mt][0] = t4v.x; bvv[(OFF) + mt][1] = t4v.y;                    \
        bvv[(OFF) + mt][2] = t4v.z; bvv[(OFF) + mt][3] = t4v.w;                    \
    }

    if (w < 2) {
        LOADW(0,  Wh1, 128, w * 64, 4, 4)
        LOADW(16, Wx1, 128, w * 64, 2, 4)
        LOADW(24, Wh4, 64,  w * 32, 2, 2)
        LOADW(28, Wx4, 64,  w * 32, 4, 2)
        LOADBF(0, b1, w * 64, 4)
        LOADBF(4, b4, w * 32, 2)
    } else if (w < 6) {
        __builtin_amdgcn_s_setprio(1);
        LOADW(0,  Wh2, 256, (w - 2) * 64, 8, 4)
        LOADW(32, Wx2, 256, (w - 2) * 64, 4, 4)
        LOADBF(0, b2, (w - 2) * 64, 4)
    } else {
        LOADW(0,  Wh3, 128, (w - 6) * 64, 4, 4)
        LOADW(16, Wx3, 128, (w - 6) * 64, 8, 4)
        LOADBF(0, b3, (w - 6) * 64, 4)
    }
#undef LOADW
#undef LOADBF

    for (int i = tid; i < 2 * 9216; i += 512) (&hall[0][0])[i] = 0;

    const unsigned short* Xs = Xb + (size_t)s * TT * 1024;
    unsigned short* H4s = H4 + (size_t)s * TT * 1024;

    // x parity prefetch into wreg[36..39]: [36,37] even t, [38,39] odd t
    if (w < 2) {
#pragma unroll
        for (int kx = 0; kx < 2; ++kx) {
            wreg[36 + kx] = *reinterpret_cast<const bf16x8*>(&Xs[kx * 512 + rdo]);
            wreg[38 + kx] = *reinterpret_cast<const bf16x8*>(&Xs[1024 + kx * 512 + rdo]);
        }
    }
    __syncthreads();

    const unsigned short* xp0 = Xs + 2 * 1024 + rdo;   // even prefetch target
    const unsigned short* xp1 = Xs + 3 * 1024 + rdo;   // odd

    const int wro1 = (w * 8 + (quad >> 1)) * 128 + l15 * 8 + (quad & 1) * 4;
    const int wro4 = 8192 + (w * 4 + (quad >> 1)) * 128 + l15 * 8 + (quad & 1) * 4;
    const int wro2 = 2048 + ((w - 2) * 8 + (quad >> 1)) * 128 + l15 * 8 + (quad & 1) * 4;
    const int wro3 = 6144 + ((w - 6) * 8 + (quad >> 1)) * 128 + l15 * 8 + (quad & 1) * 4;

    // L4 direct global store: even-macro stores odd t4; odd-macro stores even.
    unsigned short* op_e = H4s + 1024 + (wro4 - 8192);  // first even-macro t4 = 1
    unsigned short* op_o = H4s + (wro4 - 8192);         // first odd-macro  t4 = 0

#define PACKMK(ACC_MT)                                                             \
    ushort2 lo = pk2(fmaxf((ACC_MT)[0], 0.f), fmaxf((ACC_MT)[1], 0.f));            \
    ushort2 hi = pk2(fmaxf((ACC_MT)[2], 0.f), fmaxf((ACC_MT)[3], 0.f));            \
    ushort4 o; o.x = lo.x; o.y = lo.y; o.z = hi.x; o.w = hi.y;

#define STEP(TAU_, RP_, WP_, XAB, XPP, OPP)                                        \
    {                                                                              \
        const int tau_ = (TAU_);                                                   \
        const unsigned short* RB = &hall[RP_][0];                                  \
        unsigned short* WB = &hall[WP_][0];                                        \
        if (w < 2) {                                                               \
            if ((unsigned)tau_ < TT) { /* L1 */                                    \
                f32x4 acc[4];                                                      \
                _Pragma("unroll")                                                  \
                for (int mt = 0; mt < 4; ++mt)                                     \
                    acc[mt] = __builtin_amdgcn_mfma_f32_16x16x32_bf16(             \
                        wreg[16 + mt], wreg[(XAB) + 0], bvv[mt], 0, 0, 0);         \
                _Pragma("unroll")                                                  \
                for (int mt = 0; mt < 4; ++mt)                                     \
                    acc[mt] = __builtin_amdgcn_mfma_f32_16x16x32_bf16(             \
                        wreg[20 + mt], wreg[(XAB) + 1], acc[mt], 0, 0, 0);         \
                if (tau_ + 2 < TT) {                                               \
                    wreg[(XAB) + 0] = *reinterpret_cast<const bf16x8*>(XPP);       \
                    wreg[(XAB) + 1] = *reinterpret_cast<const bf16x8*>(XPP + 512); \
                    XPP += 2048;                                                   \
                }                                                                  \
                _Pragma("unroll")                                                  \
                for (int kc = 0; kc < 4; ++kc) {                                   \
                    bf16x8 af = *reinterpret_cast<const bf16x8*>(&RB[rdo + kc * 512]); \
                    _Pragma("unroll")                                              \
                    for (int mt = 0; mt < 4; ++mt)                                 \
                        acc[mt] = __builtin_amdgcn_mfma_f32_16x16x32_bf16(         \
                            wreg[kc * 4 + mt], af, acc[mt], 0, 0, 0);              \
                }                                                                  \
                _Pragma("unroll")                                                  \
                for (int mt = 0; mt < 4; ++mt) {                                   \
                    PACKMK(acc[mt])                                                \
                    *reinterpret_cast<ushort4*>(&WB[wro1 + mt * 256]) = o;         \
                }                                                                  \
            }                                                                      \
            if ((unsigned)(tau_ - 3) < TT) { /* L4 */                              \
                f32x4 acc[2];                                                      \
                {                                                                  \
                    bf16x8 af0 = *reinterpret_cast<const bf16x8*>(&RB[6144 + rdo]); \
                    _Pragma("unroll")                                              \
                    for (int mt = 0; mt < 2; ++mt)                                 \
                        acc[mt] = __builtin_amdgcn_mfma_f32_16x16x32_bf16(         \
                            wreg[28 + mt], af0, bvv[4 + mt], 0, 0, 0);             \
                }                                                                  \
                _Pragma("unroll")                                                  \
                for (int kx = 1; kx < 4; ++kx) {                                   \
                    bf16x8 af = *reinterpret_cast<const bf16x8*>(&RB[6144 + rdo + kx * 512]); \
                    _Pragma("unroll")                                              \
                    for (int mt = 0; mt < 2; ++mt)                                 \
                        acc[mt] = __builtin_amdgcn_mfma_f32_16x16x32_bf16(         \
                            wreg[28 + kx * 2 + mt], af, acc[mt], 0, 0, 0);         \
                }                                                                  \
                _Pragma("unroll")                                                  \
                for (int kc = 0; kc < 2; ++kc) {                                   \
                    bf16x8 af = *reinterpret_cast<const bf16x8*>(&RB[8192 + rdo + kc * 512]); \
                    _Pragma("unroll")                                              \
                    for (int mt = 0; mt < 2; ++mt)                                 \
                        acc[mt] = __builtin_amdgcn_mfma_f32_16x16x32_bf16(         \
                            wreg[24 + kc * 2 + mt], af, acc[mt], 0, 0, 0);         \
                }                                                                  \
                _Pragma("unroll")                                                  \
                for (int mt = 0; mt < 2; ++mt) {                                   \
                    PACKMK(acc[mt])                                                \
                    *reinterpret_cast<ushort4*>(&WB[wro4 + mt * 256]) = o;         \
                    *reinterpret_cast<ushort4*>(OPP + mt * 256) = o;               \
                }                                                                  \
                OPP += 2048;                                                       \
            }                                                                      \
        } else if (w < 6) {                                                        \
            if ((unsigned)(tau_ - 1) < TT) { /* L2 */                              \
                f32x4 acc[4];                                                      \
                {                                                                  \
                    bf16x8 af0 = *reinterpret_cast<const bf16x8*>(&RB[rdo]);       \
                    _Pragma("unroll")                                              \
                    for (int mt = 0; mt < 4; ++mt)                                 \
                        acc[mt] = __builtin_amdgcn_mfma_f32_16x16x32_bf16(         \
                            wreg[32 + mt], af0, bvv[mt], 0, 0, 0);                 \
                }                                                                  \
                _Pragma("unroll")                                                  \
                for (int kx = 1; kx < 4; ++kx) {                                   \
                    bf16x8 af = *reinterpret_cast<const bf16x8*>(&RB[rdo + kx * 512]); \
                    _Pragma("unroll")                                              \
                    for (int mt = 0; mt < 4; ++mt)                                 \
                        acc[mt] = __builtin_amdgcn_mfma_f32_16x16x32_bf16(         \
                            wreg[32 + kx * 4 + mt], af, acc[mt], 0, 0, 0);         \
                }                                                                  \
                _Pragma("unroll")                                                  \
                for (int kc = 0; kc < 8; ++kc) {                                   \
                    bf16x8 af = *reinterpret_cast<const bf16x8*>(&RB[2048 + rdo + kc * 512]); \
                    _Pragma("unroll")                                              \
                    for (int mt = 0; mt < 4; ++mt)                                 \
                        acc[mt] = __builtin_amdgcn_mfma_f32_16x16x32_bf16(         \
                            wreg[kc * 4 + mt], af, acc[mt], 0, 0, 0);              \
                }                                                                  \
                _Pragma("unroll")                                                  \
                for (int mt = 0; mt < 4; ++mt) {                                   \
                    PACKMK(acc[mt])                                                \
                    *reinterpret_cast<ushort4*>(&WB[wro2 + mt * 256]) = o;         \
                }                                                                  \
            }                                                                      \
        } else {                                                                   \
            if ((unsigned)(tau_ - 2) < TT) { /* L3 */                              \
                f32x4 acc[4];                                                      \
                {                                                                  \
                    bf16x8 af0 = *reinterpret_cast<const bf16x8*>(&RB[2048 + rdo]); \
                    _Pragma("unroll")                                              \
                    for (int mt = 0; mt < 4; ++mt)                                 \
                        acc[mt] = __builtin_amdgcn_mfma_f32_16x16x32_bf16(         \
                            wreg[16 + mt], af0, bvv[mt], 0, 0, 0);                 \
                }                                                                  \
                _Pragma("unroll")                                                  \
                for (int kx = 1; kx < 8; ++kx) {                                   \
                    bf16x8 af = *reinterpret_cast<const bf16x8*>(&RB[2048 + rdo + kx * 512]); \
                    _Pragma("unroll")                                              \
                    for (int mt = 0; mt < 4; ++mt)                                 \
                        acc[mt] = __builtin_amdgcn_mfma_f32_16x16x32_bf16(         \
                            wreg[16 + kx * 4 + mt], af, acc[mt], 0, 0, 0);         \
                }                                                                  \
                _Pragma("unroll")                                                  \
                for (int kc = 0; kc < 4; ++kc) {                                   \
                    bf16x8 af = *reinterpret_cast<const bf16x8*>(&RB[6144 + rdo + kc * 512]); \
                    _Pragma("unroll")                                              \
                    for (int mt = 0; mt < 4; ++mt)                                 \
                        acc[mt] = __builtin_amdgcn_mfma_f32_16x16x32_bf16(         \
                            wreg[kc * 4 + mt], af, acc[mt], 0, 0, 0);              \
                }                                                                  \
                _Pragma("unroll")                                                  \
                for (int mt = 0; mt < 4; ++mt) {                                   \
                    PACKMK(acc[mt])                                                \
                    *reinterpret_cast<ushort4*>(&WB[wro3 + mt * 256]) = o;         \
                }                                                                  \
            }                                                                      \
        }                                                                          \
        __builtin_amdgcn_s_waitcnt(0xC07F);                                        \
        __builtin_amdgcn_s_barrier();                                              \
    }

#pragma unroll 1
    for (int tau = 0; tau < TT + 3; tau += 2) {
        STEP(tau, 0, 1, 36, xp0, op_e)
        STEP(tau + 1, 1, 0, 38, xp1, op_o)
    }
#undef STEP
#undef PACKMK
}

// ---------------- dense stage 1: per-(s,tc) partials, no atomics ------------
__global__ __launch_bounds__(256) void dense_part(const unsigned short* __restrict__ Ht,
                                                  const float* __restrict__ Wd,
                                                  float* __restrict__ part) {
    __shared__ float red[16][17];
    const int s = blockIdx.x >> 3;
    const int tc = blockIdx.x & 7;
    const int tid = threadIdx.x;
    const int b = (tid >> 1) & 15;
    const int kbase = (tid >> 5) * 8 + (tid & 1) * 4;
    const unsigned short* base = Ht + ((size_t)s * TT + tc * 32) * 1024 + tid * 4;
    float acc = 0.f;
    for (int t = 0; t < 32; ++t) {
        ushort4 v = *reinterpret_cast<const ushort4*>(base + (size_t)t * 1024);
        const float* wd = &Wd[(tc * 32 + t) * 64 + kbase];
        acc += b2f(v.x) * wd[0] + b2f(v.y) * wd[1] + b2f(v.z) * wd[2] + b2f(v.w) * wd[3];
    }
    red[b][(tid >> 5) * 2 + (tid & 1)] = acc;
    __syncthreads();
    if (tid < 16) {
        float sum = 0.f;
#pragma unroll
        for (int j = 0; j < 16; ++j) sum += red[tid][j];
        part[blockIdx.x * 16 + tid] = sum;
    }
}

// ---------------- dense stage 2: reduce 8 partials per output ----------------
__global__ __launch_bounds__(512) void dense_final(const float* __restrict__ part,
                                                   const float* __restrict__ bd,
                                                   float* __restrict__ out) {
    const int i = threadIdx.x;          // i = s*16 + b, 512 outputs
    const int s = i >> 4, b = i & 15;
    float sum = bd[0];
#pragma unroll
    for (int tc = 0; tc < 8; ++tc) sum += part[(s * 8 + tc) * 16 + b];
    out[i] = sum;
}

extern "C" void kernel_launch(void* const* d_in, const int* in_sizes, int n_in,
                              void* d_out, int out_size, void* d_ws, size_t ws_size,
                              hipStream_t stream) {
    (void)in_sizes; (void)n_in; (void)out_size; (void)ws_size;
    const float* x   = (const float*)d_in[0];
    const float* Wx1 = (const float*)d_in[1];
    const float* Wh1 = (const float*)d_in[2];
    const float* b1  = (const float*)d_in[3];
    const float* Wx2 = (const float*)d_in[4];
    const float* Wh2 = (const float*)d_in[5];
    const float* b2  = (const float*)d_in[6];
    const float* Wx3 = (const float*)d_in[7];
    const float* Wh3 = (const float*)d_in[8];
    const float* b3  = (const float*)d_in[9];
    const float* Wx4 = (const float*)d_in[10];
    const float* Wh4 = (const float*)d_in[11];
    const float* b4  = (const float*)d_in[12];
    const float* Wd  = (const float*)d_in[13];
    const float* bd  = (const float*)d_in[14];
    float* out = (float*)d_out;

    char* ws = (char*)d_ws;
    unsigned short* xbT  = (unsigned short*)(ws);             // 16.8M
    unsigned short* H4   = (unsigned short*)(ws + 16777216);  // 16.8M
    float*          part = (float*)(ws + 2 * 16777216);       // 16 KB

    cvt_tile4<<<2048, 256, 0, stream>>>(x, xbT);

    rnn4<<<32, 512, 0, stream>>>(xbT, Wx1, Wh1, b1, Wx2, Wh2, b2,
                                 Wx3, Wh3, b3, Wx4, Wh4, b4, H4);

    dense_part<<<256, 256, 0, stream>>>(H4, Wd, part);
    dense_final<<<1, 512, 0, stream>>>(part, bd, out);
}